// Round 1
// baseline (87.476 us; speedup 1.0000x reference)
//
#include <hip/hip_runtime.h>
#include <math.h>

#define MARGIN 1.0f
#define NI 16        // i's register-blocked per pair-kernel block
#define BMAX 8192    // problem size (setup_inputs: B=8192, P=16); assumes B <= BMAX

struct Ctl {
    double sacc;
    double cacc;
    unsigned ticket;
    unsigned pad;
};

// ---------------- Kernel 1: per-row distance + accumulator init ----------------
__global__ __launch_bounds__(256) void dist_init_kernel(
    const float* __restrict__ pv,   // (B, P)
    const float* __restrict__ pt,   // (P,)
    float* __restrict__ dist,       // (B,)
    Ctl* __restrict__ ctl,
    int B, int P)
{
    int i = blockIdx.x * 256 + threadIdx.x;
    if (i == 0) { ctl->sacc = 0.0; ctl->cacc = 0.0; ctl->ticket = 0u; }
    if (i >= B) return;
    const float* row = pv + (size_t)i * P;
    float s = 0.f;
    if (P == 16) {
        // float4 loads, accumulate in index order (bit-identical to scalar chain)
        const float4* r4 = (const float4*)row;
        const float4* t4 = (const float4*)pt;
        #pragma unroll
        for (int q = 0; q < 4; ++q) {
            float4 r = r4[q], t = t4[q];
            float d0 = r.x - t.x; s = fmaf(d0, d0, s);
            float d1 = r.y - t.y; s = fmaf(d1, d1, s);
            float d2 = r.z - t.z; s = fmaf(d2, d2, s);
            float d3 = r.w - t.w; s = fmaf(d3, d3, s);
        }
    } else {
        for (int p = 0; p < P; ++p) { float d = row[p] - pt[p]; s = fmaf(d, d, s); }
    }
    dist[i] = sqrtf(s);
}

// ---------------- Kernel 2: all-pairs loss, fused finalize ----------------
__global__ __launch_bounds__(256) void pair_fused_kernel(
    const float* __restrict__ e,     // (B,) energies flat
    const float* __restrict__ dist,  // (B,)
    Ctl* __restrict__ ctl,
    float* __restrict__ out,
    int B, int nblocks)
{
    __shared__ float sd[BMAX];   // 32 KB
    __shared__ float se[BMAX];   // 32 KB  -> 64 KB total, 2 blocks/CU
    const int tid = threadIdx.x;

    // stage full dist/e arrays once (vectorized); pad with -inf (never di<dj)
    {
        const float4* d4 = (const float4*)dist;
        const float4* e4 = (const float4*)e;
        float4* sd4 = (float4*)sd;
        float4* se4 = (float4*)se;
        const int n4 = B >> 2;   // B % 4 == 0
        for (int k = tid; k < n4; k += 256) { sd4[k] = d4[k]; se4[k] = e4[k]; }
        for (int k = B + tid; k < BMAX; k += 256) { sd[k] = -INFINITY; se[k] = 0.f; }
    }
    __syncthreads();

    // register-block this block's NI i's (wave-uniform broadcast reads)
    const int i0 = blockIdx.x * NI;
    float di[NI], ai[NI];
    #pragma unroll
    for (int ii = 0; ii < NI; ++ii) {
        const bool iok = (i0 + ii) < B;
        di[ii] = iok ? sd[i0 + ii] : INFINITY;          // +inf: mask never true
        ai[ii] = iok ? (se[i0 + ii] + MARGIN) : 0.f;
    }

    // main loop: each thread walks strided j (bank = lane%32, 2-way alias = free)
    float sv[4] = {0.f, 0.f, 0.f, 0.f};
    unsigned cntw = 0;   // wave-uniform pair count via ballot/popcount (SALU pipe)

    #pragma unroll 2
    for (int s = 0; s < (BMAX / 256); ++s) {
        const int j = tid + (s << 8);
        const float dj = sd[j];
        const float ej = se[j];
        #pragma unroll
        for (int ii = 0; ii < NI; ++ii) {
            const bool m = di[ii] < dj;                 // diagonal self-excludes
            const float t = fmaxf(ai[ii] - ej, 0.f);    // relu(e_i - e_j + margin)
            sv[ii & 3] += m ? t : 0.f;
            cntw += (unsigned)__popcll(__ballot(m));
        }
    }

    // wave reduce sum; cntw already wave-uniform
    float sum = (sv[0] + sv[1]) + (sv[2] + sv[3]);
    #pragma unroll
    for (int o = 32; o > 0; o >>= 1) sum += __shfl_xor(sum, o);

    // cross-wave reduce: reuse sd/se (all reads done)
    __syncthreads();
    const int wid = tid >> 6;
    if ((tid & 63) == 0) { sd[wid] = sum; se[wid] = (float)cntw; }  // cnt <= 32768, exact
    __syncthreads();

    if (tid == 0) {
        double S = ((double)sd[0] + (double)sd[1]) + ((double)sd[2] + (double)sd[3]);
        double C = ((double)se[0] + (double)se[1]) + ((double)se[2] + (double)se[3]);
        atomicAdd(&ctl->sacc, S);
        atomicAdd(&ctl->cacc, C);
        __threadfence();
        unsigned t = atomicAdd(&ctl->ticket, 1u);
        if (t == (unsigned)(nblocks - 1)) {
            // all blocks' atomics precede their fenced ticket adds -> visible here;
            // read via atomic RMW to hit the coherent point
            double fs = atomicAdd(&ctl->sacc, 0.0);
            double fc = atomicAdd(&ctl->cacc, 0.0);
            if (fc < 1.0) fc = 1.0;
            out[0] = (float)(fs / fc);
        }
    }
}

extern "C" void kernel_launch(void* const* d_in, const int* in_sizes, int n_in,
                              void* d_out, int out_size, void* d_ws, size_t ws_size,
                              hipStream_t stream)
{
    const float* energies = (const float*)d_in[0];  // (B,1) flat = B floats
    const float* pv       = (const float*)d_in[1];  // (B,P)
    const float* pt       = (const float*)d_in[2];  // (P,)
    int B = in_sizes[0];
    int P = in_sizes[2];

    float* dist = (float*)d_ws;
    size_t coff = (((size_t)BMAX * sizeof(float)) + 255) & ~(size_t)255;
    Ctl* ctl = (Ctl*)((char*)d_ws + coff);

    int nblocks = (B + NI - 1) / NI;   // 512 for B=8192 -> exactly 2 blocks/CU

    dist_init_kernel<<<(B + 255) / 256, 256, 0, stream>>>(pv, pt, dist, ctl, B, P);
    pair_fused_kernel<<<nblocks, 256, 0, stream>>>(energies, dist, ctl, (float*)d_out, B, nblocks);
}